// Round 5
// baseline (49.315 us; speedup 1.0000x reference)
//
#include <hip/hip_runtime.h>

// ShiftDisLoss: per-box BEV corner distance loss, weighted global sum / B.
// Inputs: pred_bbox3d [B,N,7] f32, gt_bbox3d [B,N,7] f32, weights [B,N] f32.
// Output: 1 f32 scalar. B=4, N=1e6.
//
// R4 -> R5: same persistent double-buffered global_load_lds pipeline, but
// TILE 512->256 so LDS drops 63 KB -> ~31 KB => 5 blocks/CU (20 waves/CU
// instead of 8). Per wave 4 chunks/tile (uniform), counted vmcnt(4) keeps
// next-tile loads in flight across both barriers. 1280-block grid averages
// the tile-count imbalance over 5 pipelines per CU.

#define BLOCK 256
#define TILE 256                 // boxes per tile
#define NBLOCKS 1280             // 5 blocks/CU on 256 CUs
#define TILE_F 1792              // TILE*7 floats per tensor tile
#define TILE_F4 448              // TILE*7/4 float4 per tensor tile

typedef __attribute__((address_space(1))) const void gas_void;
typedef __attribute__((address_space(3))) void las_void;

__device__ __forceinline__ float fast_rcp(float x) {
    return __builtin_amdgcn_rcpf(x);
}

struct SC { float x0, y0, x1, y1, x2, y2, x3, y3; };

// Algebraic replacement of the reference's corner argsort (see R2): corners
// are c+-u, c+-v; dist^2 keys are |c|^2+|u|^2 +- 2c.u / 2c.v, so ordering
// reduces to sign/magnitude selection on t0=c.u, t1=c.v; the mid-pair x^2
// re-sort reduces to sign(cx*qx).
__device__ __forceinline__ SC sorted_corners(float cx, float cy,
                                             float dx, float dy, float h) {
    float s = __sinf(h), c = __cosf(h);
    float hx = 0.5f * dx, hy = 0.5f * dy;
    float ux = hx * c - hy * s, uy = hx * s + hy * c;
    float vx = hx * c + hy * s, vy = hx * s - hy * c;
    float t0 = cx * ux + cy * uy;
    float t1 = cx * vx + cy * vy;
    bool umajor = fabsf(t0) >= fabsf(t1);
    float px = umajor ? ux : vx, py = umajor ? uy : vy;
    float tp = umajor ? t0 : t1;
    float qx = umajor ? vx : ux, qy = umajor ? vy : uy;
    float sp = copysignf(1.0f, tp);
    float sm = copysignf(1.0f, cx * qx);
    SC r;
    r.x0 = cx - sp * px; r.y0 = cy - sp * py;   // nearest
    r.x1 = cx - sm * qx; r.y1 = cy - sm * qy;   // mid (smaller x^2)
    r.x2 = cx + sm * qx; r.y2 = cy + sm * qy;   // mid (larger x^2)
    r.x3 = cx + sp * px; r.y3 = cy + sp * py;   // farthest
    return r;
}

__device__ __forceinline__ float box_loss(float pcx, float pcy, float pdx,
                                          float pdy, float ph,
                                          float gcx, float gcy, float gdx,
                                          float gdy, float gh) {
    SC p = sorted_corners(pcx, pcy, pdx, pdy, ph);
    SC g = sorted_corners(gcx, gcy, gdx, gdy, gh);
    float d1x = g.x1 - g.x0, d1y = g.y1 - g.y0;
    float d2x = g.x2 - g.x0, d2y = g.y2 - g.y0;
    float d3x = g.x3 - g.x0, d3y = g.y3 - g.y0;
    float n1 = d1x * (p.y1 - g.y0) - d1y * (p.x1 - g.x0);
    float n2 = d2x * (p.y2 - g.y0) - d2y * (p.x2 - g.x0);
    float n3 = d3x * (p.y0 - g.y0) - d3y * (p.x0 - g.x0);
    float gx = g.x1 - g.x2, gy = g.y1 - g.y2;
    float diag = gx * gx + gy * gy;
    float sum = n1 * n1 * fast_rcp(d1x * d1x + d1y * d1y)
              + n2 * n2 * fast_rcp(d2x * d2x + d2y * d2y)
              + n3 * n3 * fast_rcp(d3x * d3x + d3y * d3y);
    return sum * fast_rcp(diag);
}

__global__ __launch_bounds__(BLOCK, 5)
void shiftdis_loss_kernel(const float* __restrict__ pred,
                          const float* __restrict__ gt,
                          const float* __restrict__ w,
                          float* __restrict__ out,
                          long long n_boxes, float inv_b) {
    __shared__ float sP[2][TILE_F];      // 2 x 7168 B
    __shared__ float sG[2][TILE_F];      // 2 x 7168 B
    __shared__ float sW[2][TILE];        // 2 x 1024 B
    __shared__ float sScratch[256];      // dummy landing (never read)
    __shared__ float wsum[4];

    const int tid = threadIdx.x;
    const int wid = tid >> 6;
    const int lane = tid & 63;

    const float4* predF4 = reinterpret_cast<const float4*>(pred);
    const float4* gtF4 = reinterpret_cast<const float4*>(gt);
    const float4* wF4 = reinterpret_cast<const float4*>(w);

    const long long nfull = n_boxes / TILE;   // full tiles
    const int G = gridDim.x;

    float acc = 0.0f;

    // Stage one tile into LDS buffer `buf`. 16 chunks of 64 float4 (1 KB):
    // 7 pred + 7 gt + 1 weights + 1 dummy, 4 per wave => uniform vmcnt.
    auto STAGE = [&](int buf, long long t) {
        const long long boxF4 = t * (long long)TILE_F4;
        const long long wbF4 = t * (long long)(TILE / 4);
#pragma unroll
        for (int k = 0; k < 4; ++k) {
            int c = wid * 4 + k;                 // 0..15 chunk id
            const float4* src;
            float* dst;
            if (c < 7) {
                src = predF4 + boxF4 + c * 64 + lane;
                dst = sP[buf] + c * 256;
            } else if (c < 14) {
                src = gtF4 + boxF4 + (c - 7) * 64 + lane;
                dst = sG[buf] + (c - 7) * 256;
            } else if (c == 14) {
                src = wF4 + wbF4 + lane;
                dst = sW[buf];
            } else {
                src = wF4 + wbF4 + lane;         // benign duplicate read
                dst = sScratch;
            }
            __builtin_amdgcn_global_load_lds((gas_void*)src, (las_void*)dst,
                                             16, 0, 0);
        }
    };

    if ((long long)blockIdx.x < nfull) {
        STAGE(0, (long long)blockIdx.x);
        int cur = 0;
        for (long long t = blockIdx.x; t < nfull; t += G) {
            long long tn = t + G;
            if (tn < nfull) {
                STAGE(cur ^ 1, tn);
                // own 4 cur-tile loads done; 4 next-tile loads stay in flight
                asm volatile("s_waitcnt vmcnt(4)" ::: "memory");
            } else {
                asm volatile("s_waitcnt vmcnt(0)" ::: "memory");
            }
            __builtin_amdgcn_sched_barrier(0);
            __builtin_amdgcn_s_barrier();      // cur tile visible to all waves
            __builtin_amdgcn_sched_barrier(0);

            {
                const float* P = sP[cur] + tid * 7;
                const float* Q = sG[cur] + tid * 7;
                float wt = sW[cur][tid];
                acc += box_loss(P[0], P[1], P[3], P[4], P[6],
                                Q[0], Q[1], Q[3], Q[4], Q[6]) * wt;
            }

            __builtin_amdgcn_sched_barrier(0);
            __builtin_amdgcn_s_barrier();      // all waves done reading cur
            __builtin_amdgcn_sched_barrier(0);
            cur ^= 1;
        }
    }

    // ragged tail (n % TILE boxes), block 0 only, direct from global
    if (blockIdx.x == 0) {
        for (long long b = nfull * TILE + tid; b < n_boxes; b += BLOCK) {
            const float* p = pred + b * 7;
            const float* q = gt + b * 7;
            acc += box_loss(p[0], p[1], p[3], p[4], p[6],
                            q[0], q[1], q[3], q[4], q[6]) * w[b];
        }
    }

    // wave-64 reduce
#pragma unroll
    for (int off = 32; off > 0; off >>= 1)
        acc += __shfl_down(acc, off, 64);

    if (lane == 0) wsum[wid] = acc;
    __syncthreads();
    if (tid == 0) {
        float bsum = wsum[0] + wsum[1] + wsum[2] + wsum[3];
        atomicAdd(out, bsum * inv_b);
    }
}

extern "C" void kernel_launch(void* const* d_in, const int* in_sizes, int n_in,
                              void* d_out, int out_size, void* d_ws, size_t ws_size,
                              hipStream_t stream) {
    const float* pred = (const float*)d_in[0];
    const float* gt   = (const float*)d_in[1];
    const float* w    = (const float*)d_in[2];
    float* out = (float*)d_out;

    long long n_boxes = (long long)in_sizes[2];   // B*N
    const float inv_b = 0.25f;                    // B = 4

    hipMemsetAsync(d_out, 0, sizeof(float), stream);

    shiftdis_loss_kernel<<<NBLOCKS, BLOCK, 0, stream>>>(pred, gt, w, out,
                                                        n_boxes, inv_b);
}